// Round 10
// baseline (133.660 us; speedup 1.0000x reference)
//
#include <hip/hip_runtime.h>
#include <math.h>

// Problem dims (fixed by setup_inputs)
#define BBATCH 8
#define TT    4096
#define II    64
#define DD    128
#define OO    64
#define PP    8
#define NTOT  (BBATCH * TT)      // 32768
#define RPB   64                 // rows per block == scan chunk
#define NBLK  (NTOT / RPB)       // 512 blocks

// Kernel A LDS: Vt dbuf 2 x 16384, W dbuf 2 x 5120 -> 43008 B -> 3 blocks/CU
#define VTBUF  0
#define WBUF   32768
#define LDSA   43008
// Kernel B LDS: HTB 64 x 264 = 16896, Ot dbuf 2 x 8192, W2 dbuf 2 x 8192 -> 49664 -> 3/CU
#define HTB    0
#define OT0    16896
#define OT1    25088
#define W2BUF  33280
#define LDSB   49664

typedef short bf16x8 __attribute__((ext_vector_type(8)));
typedef float f32x4  __attribute__((ext_vector_type(4)));

__device__ __forceinline__ unsigned short f2bf(float f) {
    union { float f; unsigned int u; } v; v.f = f;
    unsigned int r = v.u + 0x7fffu + ((v.u >> 16) & 1u);   // RNE
    return (unsigned short)(r >> 16);
}

__device__ __forceinline__ float bf2f(unsigned short b) {
    union { float f; unsigned int u; } v; v.u = ((unsigned int)b) << 16;
    return v.f;
}

__device__ __forceinline__ void gload_lds16(const void* g, void* l) {
    __builtin_amdgcn_global_load_lds(
        (const __attribute__((address_space(1))) unsigned int*)g,
        (__attribute__((address_space(3))) unsigned int*)l, 16, 0, 0);
}

// pack the 8 piecewise-linear knot weights for one scalar into 4 dwords (8 bf16)
__device__ __forceinline__ uint4 apl_w_pack(float xv) {
    float t = fminf(fmaxf((xv + 1.0f) * 3.5f, 0.0f), 7.0f);
    int idx = (int)t; if (idx > 6) idx = 6;
    float frac = t - (float)idx;
    const unsigned int b0 = f2bf(1.0f - frac);
    const unsigned int b1 = f2bf(frac);
    const int q = idx >> 1;
    const bool odd = (idx & 1) != 0;
    const unsigned int vA = odd ? (b0 << 16) : (b0 | (b1 << 16));
    const unsigned int vB = odd ? b1 : 0u;
    uint4 w;
    w.x = (q == 0) ? vA : 0u;
    w.y = (q == 1) ? vA : ((q == 0) ? vB : 0u);
    w.z = (q == 2) ? vA : ((q == 1) ? vB : 0u);
    w.w = (q == 3) ? vA : ((q == 2) ? vB : 0u);
    return w;
}

// ---------------------------------------------------------------------------
// prep_tables: LDS-staged transposes, coalesced both sides (~1-2 us).
// ---------------------------------------------------------------------------
__global__ __launch_bounds__(256) void prep_tables(
    const float* __restrict__ hv, const float* __restrict__ zv,
    const float* __restrict__ ov,
    unsigned short* __restrict__ Vt, unsigned short* __restrict__ Ot)
{
    __shared__ unsigned short lds[128 * 80];   // 20 KB, covers both tile shapes
    const int b = blockIdx.x, t = threadIdx.x;
    if (b < 32) {
        const int zsel = b & 1, kt = b >> 1;
        const int k0 = kt * 32;
        const float* src = zsel ? zv : hv;
        const int r = t >> 3, q = t & 7;
        #pragma unroll
        for (int j = 0; j < 4; ++j) {
            const float4 v = *(const float4*)(src + (size_t)(k0 + r) * 128 + j * 32 + q * 4);
            const int c0 = j * 32 + q * 4;
            lds[(c0 + 0) * 40 + r] = f2bf(v.x);
            lds[(c0 + 1) * 40 + r] = f2bf(v.y);
            lds[(c0 + 2) * 40 + r] = f2bf(v.z);
            lds[(c0 + 3) * 40 + r] = f2bf(v.w);
        }
        __syncthreads();
        #pragma unroll
        for (int p = 0; p < 2; ++p) {
            const int c = p * 64 + (t >> 2), kq = t & 3;
            const uint4 w = *(const uint4*)&lds[c * 40 + kq * 8];
            *(uint4*)(Vt + (size_t)(zsel * 128 + c) * 512 + k0 + kq * 8) = w;
        }
    } else {
        const int k0 = (b - 32) * 64;
        const int r = t >> 2, h = t & 3;
        #pragma unroll
        for (int j = 0; j < 4; ++j) {
            const float4 v = *(const float4*)(ov + (size_t)(k0 + r) * 64 + j * 16 + h * 4);
            const int c0 = j * 16 + h * 4;
            lds[(c0 + 0) * 80 + r] = f2bf(v.x);
            lds[(c0 + 1) * 80 + r] = f2bf(v.y);
            lds[(c0 + 2) * 80 + r] = f2bf(v.z);
            lds[(c0 + 3) * 80 + r] = f2bf(v.w);
        }
        __syncthreads();
        #pragma unroll
        for (int p = 0; p < 2; ++p) {
            const int c = p * 32 + (t >> 3), kq = t & 7;
            const uint4 w = *(const uint4*)&lds[c * 80 + kq * 8];
            *(uint4*)(Ot + (size_t)c * 1024 + k0 + kq * 8) = w;
        }
    }
}

// ---------------------------------------------------------------------------
// Kernel A: APL1 GEMM (round-4 loop verbatim) -> agg + bf16 panels to GLOBAL.
// No spin, no atomics, no residency constraint: 43 KB LDS -> 3 blocks/CU.
// Panels stored column-major per chunk: pan[(g*128+col)*64 + row], so kernel
// B's scan thread d reads a contiguous 128 B column.
// ---------------------------------------------------------------------------
__global__ __launch_bounds__(256, 3) void apl1_gemm(
    const float* __restrict__ x,
    const unsigned short* __restrict__ Vt,
    float* __restrict__ agg,
    unsigned short* __restrict__ hpan, unsigned short* __restrict__ zpan)
{
    __shared__ unsigned char smem[LDSA];
    const int tid = threadIdx.x;
    const int wave = tid >> 6, lane = tid & 63;
    const int g = blockIdx.x;
    const int n0 = g * RPB;
    const int m = lane & 15, u = lane >> 4;

    float xs[16];
    {
        const float* xp = x + (size_t)(n0 + (tid >> 2)) * II + (tid & 3);
        #pragma unroll
        for (int c = 0; c < 16; ++c) xs[c] = __builtin_nontemporal_load(xp + 4 * c);
    }

    auto stageVt = [&](int c, int bi) {
        unsigned char* buf = smem + VTBUF + bi * 16384;
        #pragma unroll
        for (int j = 0; j < 4; ++j) {
            const int r0 = wave * 64 + j * 16;
            const int r = r0 + (lane >> 2);
            const int ug = (lane & 3) ^ ((r >> 2) & 3);
            gload_lds16((const unsigned char*)Vt + (size_t)r * 1024 + c * 64 + ug * 16,
                        buf + r0 * 64);
        }
    };
    auto buildW = [&](int c, int bi) {
        const int n = tid >> 2, ib = tid & 3;
        uint4 w = apl_w_pack(xs[c]);
        *(uint4*)(smem + WBUF + bi * 5120 + n * 80 + ib * 16) = w;   // padded, no XOR
    };

    const int colbase = wave * 64;       // waves 0,1: h cols; 2,3: z cols
    f32x4 acc[4][4];
    #pragma unroll
    for (int tr = 0; tr < 4; ++tr)
        #pragma unroll
        for (int tc = 0; tc < 4; ++tc)
            acc[tr][tc] = (f32x4){0.f, 0.f, 0.f, 0.f};

    stageVt(0, 0);
    buildW(0, 0);
    __syncthreads();                     // full drain once (x loads + tile 0)

    for (int c = 0; c < 16; ++c) {
        if (c < 15) {
            stageVt(c + 1, (c + 1) & 1);           // +4 vmcnt per wave
            buildW(c + 1, (c + 1) & 1);
            asm volatile("s_waitcnt vmcnt(4) lgkmcnt(0)" ::: "memory");  // tile c landed; c+1 in flight
        } else {
            asm volatile("s_waitcnt vmcnt(0) lgkmcnt(0)" ::: "memory");
        }
        __builtin_amdgcn_sched_barrier(0);
        __builtin_amdgcn_s_barrier();              // barrier #1: tile c visible to all
        __builtin_amdgcn_sched_barrier(0);

        const int bi = c & 1;
        bf16x8 a[4], bb[4];
        #pragma unroll
        for (int tr = 0; tr < 4; ++tr) {
            const int r = tr * 16 + m;
            a[tr] = *(const bf16x8*)(smem + WBUF + bi * 5120 + r * 80 + u * 16);
        }
        #pragma unroll
        for (int tc = 0; tc < 4; ++tc) {
            const int rc = colbase + tc * 16 + m;
            bb[tc] = *(const bf16x8*)(smem + VTBUF + bi * 16384 + rc * 64 + ((u ^ ((rc >> 2) & 3)) * 16));
        }
        #pragma unroll
        for (int tr = 0; tr < 4; ++tr)
            #pragma unroll
            for (int tc = 0; tc < 4; ++tc)
                acc[tr][tc] = __builtin_amdgcn_mfma_f32_16x16x32_bf16(a[tr], bb[tc], acc[tr][tc], 0, 0, 0);

        __builtin_amdgcn_sched_barrier(0);
        __builtin_amdgcn_s_barrier();              // barrier #2: reads of tile c complete
    }

    // aggregates (waves 0,1 hold h cols 0..127) -> plain global stores
    if (wave < 2) {
        #pragma unroll
        for (int tc = 0; tc < 4; ++tc) {
            float s = 0.0f;
            #pragma unroll
            for (int tr = 0; tr < 4; ++tr) {
                f32x4 v = acc[tr][tc];
                s += v[0] + v[1] + v[2] + v[3];
            }
            s += __shfl_xor(s, 16);
            s += __shfl_xor(s, 32);
            if ((lane >> 4) == 0)
                agg[(size_t)g * 128 + colbase + tc * 16 + lane] = s;
        }
    }

    // panels -> global, column-major per chunk (8 B/thread, nontemporal)
    #pragma unroll
    for (int tr = 0; tr < 4; ++tr) {
        #pragma unroll
        for (int tc = 0; tc < 4; ++tc) {
            const int col = colbase + tc * 16 + m;
            const int r0 = tr * 16 + u * 4;
            f32x4 v = acc[tr][tc];
            union { ushort4 p4; unsigned long long q; } pk;
            if (col < 128) {
                pk.p4.x = f2bf(v[0]); pk.p4.y = f2bf(v[1]);
                pk.p4.z = f2bf(v[2]); pk.p4.w = f2bf(v[3]);
                __builtin_nontemporal_store(pk.q,
                    (unsigned long long*)(hpan + ((size_t)g * 128 + col) * 64 + r0));
            } else {
                pk.p4.x = f2bf(1.0f / (1.0f + __expf(-v[0])));
                pk.p4.y = f2bf(1.0f / (1.0f + __expf(-v[1])));
                pk.p4.z = f2bf(1.0f / (1.0f + __expf(-v[2])));
                pk.p4.w = f2bf(1.0f / (1.0f + __expf(-v[3])));
                __builtin_nontemporal_store(pk.q,
                    (unsigned long long*)(zpan + ((size_t)g * 128 + (col - 128)) * 64 + r0));
            }
        }
    }
}

// ---------------------------------------------------------------------------
// Kernel B: prefix (plain loads; kernel boundary guarantees visibility) ->
// z-mix scan -> APL2 GEMM (round-4 Phase C verbatim).  48.5 KB -> 3 blocks/CU.
// ---------------------------------------------------------------------------
__global__ __launch_bounds__(256, 3) void scan_apl2(
    const float* __restrict__ h0,
    const unsigned short* __restrict__ Ot,
    const float* __restrict__ agg,
    const unsigned short* __restrict__ hpan, const unsigned short* __restrict__ zpan,
    float* __restrict__ ht_out, float* __restrict__ y)
{
    __shared__ unsigned char smem[LDSB];
    const int tid = threadIdx.x;
    const int wave = tid >> 6, lane = tid & 63;
    const int g = blockIdx.x;
    const int n0 = g * RPB;
    const int b = g >> 6, lb = g & 63;
    const int m = lane & 15, u = lane >> 4;

    auto stageOt = [&](int c, unsigned char* buf) {
        #pragma unroll
        for (int j = 0; j < 2; ++j) {
            const int r0 = wave * 16 + j * 8;
            const int r = r0 + (lane >> 3);
            const int ug = (lane & 7) ^ (r & 7);
            gload_lds16((const unsigned char*)Ot + (size_t)r * 2048 + c * 128 + ug * 16,
                        buf + r0 * 128);
        }
    };
    stageOt(0, smem + OT0);              // overlap Ot tile 0 with prefix+scan

    // ---------------- prefix + z-mix scan -> ht + HTB -----------------------
    if (tid < 128) {
        const int d = tid;
        float run = h0[(size_t)b * 128 + d];
        const float* ap = agg + (size_t)(b * 64) * 128 + d;
        float t[16];
        #pragma unroll
        for (int j = 0; j < 16; ++j) t[j] = 0.0f;
        #pragma unroll
        for (int j = 0; j < 63; ++j) {
            if (j < lb) t[j & 15] += ap[(size_t)j * 128];
        }
        #pragma unroll
        for (int j = 8; j < 16; ++j) t[j - 8] += t[j];
        #pragma unroll
        for (int j = 4; j < 8; ++j) t[j - 4] += t[j];
        run += (t[0] + t[1]) + (t[2] + t[3]);

        const unsigned long long* hcol =
            (const unsigned long long*)(hpan + ((size_t)g * 128 + d) * 64);
        const unsigned long long* zcol =
            (const unsigned long long*)(zpan + ((size_t)g * 128 + d) * 64);
        #pragma unroll
        for (int rq = 0; rq < 16; ++rq) {
            union { unsigned long long q; ushort4 p4; } hq, zq;
            hq.q = __builtin_nontemporal_load(hcol + rq);
            zq.q = __builtin_nontemporal_load(zcol + rq);
            const unsigned short* hp = (const unsigned short*)&hq.p4;
            const unsigned short* zp = (const unsigned short*)&zq.p4;
            #pragma unroll
            for (int kk = 0; kk < 4; ++kk) {
                const int r = rq * 4 + kk;
                float hb = bf2f(hp[kk]);
                float zt = bf2f(zp[kk]);
                run += hb;
                float htv = (1.0f - zt) * run + zt * hb;
                __builtin_nontemporal_store(htv, ht_out + (size_t)(n0 + r) * DD + d);
                *(unsigned short*)(smem + HTB + r * 264 + d * 2) = f2bf(htv);  // 264-B stride
            }
        }
    }
    __syncthreads();                     // HTB ready; OT0 DMA drained

    // ---------------- Phase C: y(64 x 64) = W2(64 x 1024) x Ot^T ------------
    auto buildW2 = [&](int c, int bi) {
        unsigned char* wb = smem + W2BUF + bi * 8192;
        const int n = tid >> 2, dl2 = tid & 3;
        unsigned int pair = *(const unsigned int*)(smem + HTB + n * 264 + (c * 8 + 2 * dl2) * 2);
        uint4 w0 = apl_w_pack(bf2f((unsigned short)(pair & 0xffffu)));
        uint4 w1 = apl_w_pack(bf2f((unsigned short)(pair >> 16)));
        *(uint4*)(wb + n * 128 + (((2 * dl2)     ^ (n & 7)) * 16)) = w0;
        *(uint4*)(wb + n * 128 + (((2 * dl2 + 1) ^ (n & 7)) * 16)) = w1;
    };

    buildW2(0, 0);
    __syncthreads();

    const int wr = wave >> 1, wc = wave & 1;
    f32x4 acc2[2][2];
    #pragma unroll
    for (int tr = 0; tr < 2; ++tr)
        #pragma unroll
        for (int tc = 0; tc < 2; ++tc)
            acc2[tr][tc] = (f32x4){0.f, 0.f, 0.f, 0.f};

    for (int c = 0; c < 16; ++c) {
        if (c < 15) {
            stageOt(c + 1, smem + (((c + 1) & 1) ? OT1 : OT0));   // +2 vmcnt per wave
            buildW2(c + 1, (c + 1) & 1);
            asm volatile("s_waitcnt vmcnt(2) lgkmcnt(0)" ::: "memory");  // tile c landed; c+1 in flight
        } else {
            asm volatile("s_waitcnt vmcnt(0) lgkmcnt(0)" ::: "memory");
        }
        __builtin_amdgcn_sched_barrier(0);
        __builtin_amdgcn_s_barrier();              // barrier #1: tile c visible
        __builtin_amdgcn_sched_barrier(0);

        unsigned char* wb = smem + W2BUF + (c & 1) * 8192;
        unsigned char* ob = smem + ((c & 1) ? OT1 : OT0);
        #pragma unroll
        for (int s = 0; s < 2; ++s) {
            const int pos = s * 4 + u;
            bf16x8 a2[2], b2[2];
            #pragma unroll
            for (int tr = 0; tr < 2; ++tr) {
                const int r = wr * 32 + tr * 16 + m;
                a2[tr] = *(const bf16x8*)(wb + r * 128 + ((pos ^ (r & 7)) * 16));
            }
            #pragma unroll
            for (int tc = 0; tc < 2; ++tc) {
                const int rc = wc * 32 + tc * 16 + m;
                b2[tc] = *(const bf16x8*)(ob + rc * 128 + ((pos ^ (rc & 7)) * 16));
            }
            #pragma unroll
            for (int tr = 0; tr < 2; ++tr)
                #pragma unroll
                for (int tc = 0; tc < 2; ++tc)
                    acc2[tr][tc] = __builtin_amdgcn_mfma_f32_16x16x32_bf16(a2[tr], b2[tc], acc2[tr][tc], 0, 0, 0);
        }

        __builtin_amdgcn_sched_barrier(0);
        __builtin_amdgcn_s_barrier();              // barrier #2: reads of tile c complete
    }

    #pragma unroll
    for (int tr = 0; tr < 2; ++tr)
        #pragma unroll
        for (int tc = 0; tc < 2; ++tc) {
            const int col = wc * 32 + tc * 16 + m;
            const int n = n0 + wr * 32 + tr * 16 + u * 4;
            f32x4 v = acc2[tr][tc];
            #pragma unroll
            for (int rg = 0; rg < 4; ++rg)
                __builtin_nontemporal_store(v[rg], y + (size_t)(n + rg) * OO + col);
        }
}

// ---------------------------------------------------------------------------
extern "C" void kernel_launch(void* const* d_in, const int* in_sizes, int n_in,
                              void* d_out, int out_size, void* d_ws, size_t ws_size,
                              hipStream_t stream) {
    const float* x  = (const float*)d_in[0];   // (B,T,I)
    const float* h0 = (const float*)d_in[1];   // (B,D)
    const float* zv = (const float*)d_in[2];   // (I,P,D)
    const float* hv = (const float*)d_in[3];   // (I,P,D)
    const float* ov = (const float*)d_in[4];   // (D,P,O)

    float* y  = (float*)d_out;                           // (B,T,O)
    float* ht = (float*)d_out + (size_t)NTOT * OO;       // (B,T,D)

    float* agg = (float*)d_ws;                                        // 512*128 f32
    unsigned short* Vt  = (unsigned short*)(agg + (size_t)NBLK * 128);   // 256x512
    unsigned short* Ot  = Vt + 256 * 512;                                // 64x1024
    unsigned short* hpan = Ot + 64 * 1024;                               // 512*128*64
    unsigned short* zpan = hpan + (size_t)NBLK * 128 * 64;               // 512*128*64

    prep_tables<<<48, 256, 0, stream>>>(hv, zv, ov, Vt, Ot);
    apl1_gemm<<<NBLK, 256, 0, stream>>>(x, Vt, agg, hpan, zpan);
    scan_apl2<<<NBLK, 256, 0, stream>>>(h0, Ot, agg, hpan, zpan, ht, y);
}